// Round 20
// baseline (327.637 us; speedup 1.0000x reference)
//
#include <hip/hip_runtime.h>
#include <hip/hip_fp16.h>
#include <math.h>

#define NN 100000
#define NE 3200000
#define FIN 256
#define NEG 0.2f
#define BSH 7                 // 128 nodes per bucket
#define NB  782               // ceil(NN/128)
#define NBP 784               // padded
#define EPB 2048              // edges per binning block (halved: widen grid)
#define NBLK 1563             // ceil(NE/EPB)
#define CAPB 8192             // binB LDS capacity

typedef _Float16 h8 __attribute__((ext_vector_type(8)));
typedef float f32x4 __attribute__((ext_vector_type(4)));

// ---------------- W1 -> fp16 B-fragment layout ----------------
__global__ __launch_bounds__(256) void k_w1h(const float* __restrict__ W1,
                                             __half* __restrict__ w1frag) {
  int f = blockIdx.x * 256 + threadIdx.x;     // 64 blocks -> 16384
  int j = f & 7;
  int lane = (f >> 3) & 63;
  int g = f >> 9;                             // 0..31
  int ks = g & 7, ct = g >> 3;
  int k = ks * 32 + ((lane >> 4) & 3) * 8 + j;
  int c = ct * 16 + (lane & 15);
  w1frag[f] = __float2half(W1[k * 64 + c]);
}

// ---------------- GEMM1 via MFMA ----------------
__global__ __launch_bounds__(256) void k_gemm1(
    const float* __restrict__ x, const __half* __restrict__ w1frag,
    __half* __restrict__ feat1h) {
  const int lane = threadIdx.x & 63;
  const int wave = threadIdx.x >> 6;
  const int rowBase = blockIdx.x * 64 + wave * 16;
  const int arow = rowBase + (lane & 15);
  const int kc = lane >> 4;
  const bool act = (arow < NN);
  f32x4 acc0 = {0.f,0.f,0.f,0.f}, acc1 = {0.f,0.f,0.f,0.f};
  f32x4 acc2 = {0.f,0.f,0.f,0.f}, acc3 = {0.f,0.f,0.f,0.f};
  const float4* __restrict__ x4 = reinterpret_cast<const float4*>(x);
  const h8* __restrict__ wf = reinterpret_cast<const h8*>(w1frag);
#pragma unroll
  for (int ks = 0; ks < 8; ++ks) {
    h8 a;
    if (act) {
      float4 xa = x4[(size_t)arow * 64 + ks * 8 + kc * 2];
      float4 xb = x4[(size_t)arow * 64 + ks * 8 + kc * 2 + 1];
      a[0] = (_Float16)xa.x; a[1] = (_Float16)xa.y;
      a[2] = (_Float16)xa.z; a[3] = (_Float16)xa.w;
      a[4] = (_Float16)xb.x; a[5] = (_Float16)xb.y;
      a[6] = (_Float16)xb.z; a[7] = (_Float16)xb.w;
    } else {
#pragma unroll
      for (int j = 0; j < 8; ++j) a[j] = (_Float16)0.f;
    }
    h8 b0 = wf[(0 * 8 + ks) * 64 + lane];
    h8 b1 = wf[(1 * 8 + ks) * 64 + lane];
    h8 b2 = wf[(2 * 8 + ks) * 64 + lane];
    h8 b3 = wf[(3 * 8 + ks) * 64 + lane];
    acc0 = __builtin_amdgcn_mfma_f32_16x16x32_f16(a, b0, acc0, 0, 0, 0);
    acc1 = __builtin_amdgcn_mfma_f32_16x16x32_f16(a, b1, acc1, 0, 0, 0);
    acc2 = __builtin_amdgcn_mfma_f32_16x16x32_f16(a, b2, acc2, 0, 0, 0);
    acc3 = __builtin_amdgcn_mfma_f32_16x16x32_f16(a, b3, acc3, 0, 0, 0);
  }
  const int crow = rowBase + (lane >> 4) * 4;
  const int ccol = lane & 15;
#pragma unroll
  for (int r = 0; r < 4; ++r) {
    int row = crow + r;
    if (row < NN) {
      __half* fr = feat1h + (size_t)row * 64 + ccol;
      fr[0]  = __float2half(acc0[r]);
      fr[16] = __float2half(acc1[r]);
      fr[32] = __float2half(acc2[r]);
      fr[48] = __float2half(acc3[r]);
    }
  }
}

// ---------------- er1 from feat1h (el1 recomputed on the fly in agg1) ----------------
__global__ __launch_bounds__(256) void k_er1(
    const __half* __restrict__ feat1h, const float* __restrict__ ar1,
    float* __restrict__ er1) {
  const int g = blockIdx.x * 256 + threadIdx.x;   // 800000 = 3125*256
  const int n = g >> 3, h = g & 7;
  uint4 rv = *reinterpret_cast<const uint4*>(feat1h + (size_t)n * 64 + h * 8);
  float f[8];
  {
    unsigned w0 = rv.x, w1 = rv.y, w2 = rv.z, w3 = rv.w;
    float2 f0 = __half22float2(*reinterpret_cast<__half2*>(&w0));
    float2 f1 = __half22float2(*reinterpret_cast<__half2*>(&w1));
    float2 f2 = __half22float2(*reinterpret_cast<__half2*>(&w2));
    float2 f3 = __half22float2(*reinterpret_cast<__half2*>(&w3));
    f[0]=f0.x; f[1]=f0.y; f[2]=f1.x; f[3]=f1.y;
    f[4]=f2.x; f[5]=f2.y; f[6]=f3.x; f[7]=f3.y;
  }
  float pr = 0.f;
#pragma unroll
  for (int j = 0; j < 8; ++j) pr = fmaf(f[j], ar1[h * 8 + j], pr);
  er1[g] = pr;
}

// ---------------- bucket histogram ----------------
__global__ __launch_bounds__(256) void k_hist(const int* __restrict__ dst,
                                              int* __restrict__ bcnt) {
  __shared__ int lcnt[NBP];
  for (int i = threadIdx.x; i < NBP; i += 256) lcnt[i] = 0;
  __syncthreads();
  const int base = blockIdx.x * EPB;
  const int n = min(EPB, NE - base);
  for (int k = threadIdx.x; k < n; k += 256)
    atomicAdd(&lcnt[dst[base + k] >> BSH], 1);
  __syncthreads();
  for (int i = threadIdx.x; i < NB; i += 256)
    if (lcnt[i]) atomicAdd(&bcnt[i], lcnt[i]);
}

// ---------------- scan buckets -> bbase, cursor ----------------
__global__ __launch_bounds__(256) void k_bscan(const int* __restrict__ bcnt,
    int* __restrict__ bbase, int* __restrict__ cursor) {
  __shared__ int part[256];
  const int t = threadIdx.x;
  int v[4]; int s = 0;
#pragma unroll
  for (int j = 0; j < 4; ++j) { int i = t*4+j; v[j] = (i < NB) ? bcnt[i] : 0; s += v[j]; }
  part[t] = s; __syncthreads();
  for (int off = 1; off < 256; off <<= 1) {
    int a = (t >= off) ? part[t-off] : 0;
    __syncthreads(); part[t] += a; __syncthreads();
  }
  int excl = (t > 0) ? part[t-1] : 0;
#pragma unroll
  for (int j = 0; j < 4; ++j) {
    int i = t*4+j;
    if (i < NB) { bbase[i] = excl; cursor[i] = excl; }
    excl += v[j];
  }
  if (t == 255) bbase[NB] = part[255];   // == NE
}

// ---------------- phase A: bin edges by bucket (slim LDS, few barriers, wide grid) ----------------
__global__ __launch_bounds__(256) void k_binA(const int* __restrict__ src,
    const int* __restrict__ dst, int* __restrict__ cursor, int* __restrict__ pairs) {
  __shared__ int cnt[NBP];
  __shared__ int bstart[NBP + 1];   // exclusive starts; becomes bucket ENDs after scatter
  __shared__ int gbase[NBP];
  __shared__ int pack[EPB];
  __shared__ int wsum[4];
  const int t = threadIdx.x;
  const int base = blockIdx.x * EPB;
  const int n = min(EPB, NE - base);
  for (int i = t; i < NBP; i += 256) cnt[i] = 0;
  __syncthreads();
  for (int k = t; k < n; k += 256) atomicAdd(&cnt[dst[base+k] >> BSH], 1);
  __syncthreads();
  // exclusive scan cnt -> bstart, shfl-based (2 barriers)
  int v[4]; int s = 0;
#pragma unroll
  for (int j = 0; j < 4; ++j) { int i = t*4+j; v[j] = (i < NBP) ? cnt[i] : 0; s += v[j]; }
  const int lanev = t & 63, wv = t >> 6;
  int inc = s;
#pragma unroll
  for (int dlt = 1; dlt < 64; dlt <<= 1) {
    int o = __shfl_up(inc, dlt);
    if (lanev >= dlt) inc += o;
  }
  if (lanev == 63) wsum[wv] = inc;
  __syncthreads();
  int wadd = 0;
  for (int w = 0; w < wv; ++w) wadd += wsum[w];
  int excl = wadd + inc - s;
#pragma unroll
  for (int j = 0; j < 4; ++j) {
    int i = t*4+j;
    if (i < NBP) bstart[i] = excl;
    excl += v[j];
  }
  if (t == 255) bstart[NBP] = excl;
  // reserve disjoint global ranges per bucket (cnt stable)
  for (int b = t; b < NB; b += 256)
    if (cnt[b]) gbase[b] = atomicAdd(&cursor[b], cnt[b]);
  __syncthreads();
  // local scatter: atomicAdd on bstart in place (bstart[b] -> end of bucket b)
  for (int k = t; k < n; k += 256) {
    int d = dst[base+k];
    int b = d >> BSH;
    int pos = atomicAdd(&bstart[b], 1);
    pack[pos] = src[base+k] | ((d & 127) << 20);
  }
  __syncthreads();
  // stream out: recover bucket via binary search over ends
  for (int i = t; i < n; i += 256) {
    int lo = 0, hi = NB - 1;
    while (lo < hi) {
      int mid = (lo + hi) >> 1;
      if (bstart[mid] > i) hi = mid; else lo = mid + 1;
    }
    const int b = lo;
    const int sb = (b > 0) ? bstart[b-1] : 0;   // post-scatter bstart[b-1] == original start of b
    pairs[gbase[b] + (i - sb)] = pack[i];
  }
}

// ---------------- phase B: per-bucket counting sort -> csr, offs, deg ----------------
__global__ __launch_bounds__(256) void k_binB(const int* __restrict__ bbase,
    const int* __restrict__ pairs, int* __restrict__ csr,
    int* __restrict__ offs, int* __restrict__ deg) {
  __shared__ int hist[128];
  __shared__ int incl[128];
  __shared__ int lcur[128];
  __shared__ int out[CAPB];
  const int b = blockIdx.x;
  const int t = threadIdx.x;
  const int lo = bbase[b], hi = bbase[b+1];
  const int n = hi - lo;
  if (t < 128) { hist[t] = 0; lcur[t] = 0; }
  __syncthreads();
  for (int k = t; k < n; k += 256) atomicAdd(&hist[(pairs[lo+k] >> 20) & 127], 1);
  __syncthreads();
  if (t < 128) incl[t] = hist[t];
  __syncthreads();
  for (int off = 1; off < 128; off <<= 1) {
    int a = (t < 128 && t >= off) ? incl[t-off] : 0;
    __syncthreads();
    if (t < 128) incl[t] += a;
    __syncthreads();
  }
  if (t < 128) {
    int gnode = b*128 + t;
    if (gnode < NN) {
      offs[gnode] = lo + ((t > 0) ? incl[t-1] : 0);
      deg[gnode]  = hist[t];
    }
  }
  __syncthreads();
  for (int k = t; k < n; k += 256) {
    int v = pairs[lo+k];
    int node = (v >> 20) & 127;
    int e = (node > 0) ? incl[node-1] : 0;
    int pos = e + atomicAdd(&lcur[node], 1);
    if (pos < CAPB) out[pos] = v & 0xFFFFF;
  }
  __syncthreads();
  for (int i = t; i < n && i < CAPB; i += 256) csr[lo+i] = out[i];
}

// ---------------- layer-1 aggregation: el computed on the fly from the gathered feat row ----------------
__global__ __launch_bounds__(64) void k_agg1(
    const __half* __restrict__ feat1h, const float* __restrict__ al1,
    const float* __restrict__ er1, const float* __restrict__ b1,
    const int* __restrict__ offs, const int* __restrict__ deg,
    const int* __restrict__ csr_src, float* __restrict__ h1) {
  const int d = blockIdx.x;
  const int lane = threadIdx.x;
  const int e8 = lane >> 3;    // edge slot 0..7
  const int h  = lane & 7;     // head 0..7
  const int off = offs[d];
  const int n = deg[d];
  const float erd = er1[d*8 + h];
  float a1[8];
#pragma unroll
  for (int k = 0; k < 8; ++k) a1[k] = al1[h*8 + k];
  int sAll = (lane < n) ? csr_src[off + lane] : 0;
  float ss = 0.f;
  float ac[8];
#pragma unroll
  for (int k = 0; k < 8; ++k) ac[k] = 0.f;
#pragma unroll 2
  for (int j0 = 0; j0 < n; j0 += 8) {
    const int j = j0 + e8;
    const bool act = (j < n);
    const int sreg = __shfl(sAll, j & 63);
    int s;
    if (j0 + 7 < 64) s = sreg;
    else s = act ? ((j < 64) ? sreg : csr_src[off + j]) : 0;
    uint4 rv = make_uint4(0u,0u,0u,0u);
    if (act) rv = *reinterpret_cast<const uint4*>(feat1h + (size_t)s*64 + h*8);
    float f[8];
    {
      unsigned w0 = rv.x, w1 = rv.y, w2 = rv.z, w3 = rv.w;
      float2 f0 = __half22float2(*reinterpret_cast<__half2*>(&w0));
      float2 f1 = __half22float2(*reinterpret_cast<__half2*>(&w1));
      float2 f2 = __half22float2(*reinterpret_cast<__half2*>(&w2));
      float2 f3 = __half22float2(*reinterpret_cast<__half2*>(&w3));
      f[0]=f0.x; f[1]=f0.y; f[2]=f1.x; f[3]=f1.y;
      f[4]=f2.x; f[5]=f2.y; f[6]=f3.x; f[7]=f3.y;
    }
    float elv = 0.f;
#pragma unroll
    for (int k = 0; k < 8; ++k) elv = fmaf(f[k], a1[k], elv);
    float t = elv + erd;
    float e = (t > 0.f) ? t : NEG * t;
    float p = act ? __expf(e) : 0.f;
    ss += p;
#pragma unroll
    for (int k = 0; k < 8; ++k) ac[k] = fmaf(p, f[k], ac[k]);
  }
#pragma unroll
  for (int msk = 8; msk < 64; msk <<= 1) {
    ss += __shfl_xor(ss, msk);
#pragma unroll
    for (int k = 0; k < 8; ++k) ac[k] += __shfl_xor(ac[k], msk);
  }
  if (e8 == 0) {
    float invS = (ss > 0.f) ? 1.f / ss : 0.f;
    float o[8];
#pragma unroll
    for (int k = 0; k < 8; ++k) {
      float v = ac[k] * invS + b1[h*8 + k];
      o[k] = (v > 0.f) ? v : 0.f;
    }
    float4* p4 = reinterpret_cast<float4*>(h1 + (size_t)d*64 + h*8);
    p4[0] = make_float4(o[0], o[1], o[2], o[3]);
    p4[1] = make_float4(o[4], o[5], o[6], o[7]);
  }
}

// ---------------- GEMM2: feat2p[N,64pad] = h1 @ W2; el2 (fp32) embedded at ch 40-41 ----------------
__global__ __launch_bounds__(64) void k_gemm2(
    const float* __restrict__ h1, const float* __restrict__ W2,
    const float* __restrict__ al2, const float* __restrict__ ar2,
    __half* __restrict__ feat2p, float* __restrict__ er2) {
  const int n = blockIdx.x;
  const int c = threadIdx.x;
  const float* __restrict__ hr = h1 + (size_t)n*64;
  float acc = 0.f;
  if (c < 40) {
    for (int k = 0; k < 64; ++k)
      acc = fmaf(hr[k], W2[k*40 + c], acc);
    feat2p[(size_t)n*64 + c] = __float2half(acc);   // 128-B aligned padded row
  } else if (c >= 42) {
    feat2p[(size_t)n*64 + c] = __ushort_as_half((unsigned short)0);
  }
  float pl = (c < 40) ? acc * al2[c] : 0.f;
  float pr = (c < 40) ? acc * ar2[c] : 0.f;
#pragma unroll
  for (int msk = 32; msk >= 1; msk >>= 1) {
    pl += __shfl_xor(pl, msk);
    pr += __shfl_xor(pr, msk);
  }
  if (c == 0) {
    er2[n] = pr;
    *reinterpret_cast<float*>(feat2p + (size_t)n*64 + 40) = pl;
  }
}

// ---------------- layer-2: single-pass no-max softmax, el2 read from padded row ----------------
__global__ __launch_bounds__(64) void k_agg2(
    const __half* __restrict__ feat2p,
    const float* __restrict__ er2, const float* __restrict__ b2,
    const int* __restrict__ offs, const int* __restrict__ deg,
    const int* __restrict__ csr_src, float* __restrict__ out) {
  const int d = blockIdx.x;
  const int lane = threadIdx.x;
  const int e8 = lane >> 3;    // edge slot 0..7
  const int q8 = lane & 7;     // 16-B chunk 0..7
  const bool ldr = (q8 < 6);   // chunks 0..5 loaded (5 = el2)
  const bool real = (q8 < 5);  // feat chunks
  const int off = offs[d];
  const int n = deg[d];
  const float erd = er2[d];
  const int elLane = e8 * 8 + 5;
  int sAll = (lane < n) ? csr_src[off + lane] : 0;
  float ss = 0.f;
  float ac[8];
#pragma unroll
  for (int k = 0; k < 8; ++k) ac[k] = 0.f;
#pragma unroll 2
  for (int j0 = 0; j0 < n; j0 += 8) {
    const int j = j0 + e8;
    const bool act = (j < n);
    const int sreg = __shfl(sAll, j & 63);
    int s;
    if (j0 + 7 < 64) s = sreg;
    else s = act ? ((j < 64) ? sreg : csr_src[off + j]) : 0;
    uint4 rv = make_uint4(0u,0u,0u,0u);
    if (act && ldr) rv = *reinterpret_cast<const uint4*>(feat2p + (size_t)s*64 + q8*8);
    float elv = __shfl(__int_as_float((int)rv.x), elLane);
    float f[8];
    {
      unsigned w0 = rv.x, w1 = rv.y, w2 = rv.z, w3 = rv.w;
      float2 f0 = __half22float2(*reinterpret_cast<__half2*>(&w0));
      float2 f1 = __half22float2(*reinterpret_cast<__half2*>(&w1));
      float2 f2 = __half22float2(*reinterpret_cast<__half2*>(&w2));
      float2 f3 = __half22float2(*reinterpret_cast<__half2*>(&w3));
      f[0]=f0.x; f[1]=f0.y; f[2]=f1.x; f[3]=f1.y;
      f[4]=f2.x; f[5]=f2.y; f[6]=f3.x; f[7]=f3.y;
    }
    float t = elv + erd;
    float e = (t > 0.f) ? t : NEG * t;
    float p = act ? __expf(e) : 0.f;
    ss += p;
#pragma unroll
    for (int k = 0; k < 8; ++k) ac[k] = fmaf(p, f[k], ac[k]);
  }
#pragma unroll
  for (int msk = 8; msk < 64; msk <<= 1) {
    ss += __shfl_xor(ss, msk);
#pragma unroll
    for (int k = 0; k < 8; ++k) ac[k] += __shfl_xor(ac[k], msk);
  }
  if (e8 == 0 && real) {
    float invS = (ss > 0.f) ? 1.f / ss : 0.f;
    float o[8];
#pragma unroll
    for (int k = 0; k < 8; ++k) o[k] = ac[k] * invS + b2[q8*8 + k];
    float* po = out + (size_t)d*40 + q8*8;
#pragma unroll
    for (int k = 0; k < 8; ++k) po[k] = o[k];
  }
}

extern "C" void kernel_launch(void* const* d_in, const int* in_sizes, int n_in,
                              void* d_out, int out_size, void* d_ws, size_t ws_size,
                              hipStream_t stream) {
  const float* x   = (const float*)d_in[0];
  const float* W1  = (const float*)d_in[1];
  const float* al1 = (const float*)d_in[2];
  const float* ar1 = (const float*)d_in[3];
  const float* b1  = (const float*)d_in[4];
  const float* W2  = (const float*)d_in[5];
  const float* al2 = (const float*)d_in[6];
  const float* ar2 = (const float*)d_in[7];
  const float* b2  = (const float*)d_in[8];
  const int* src   = (const int*)d_in[9];
  const int* dst   = (const int*)d_in[10];
  float* out = (float*)d_out;

  char* ws = (char*)d_ws;
  size_t o = 0;
  auto alloc = [&](size_t bytes) -> void* {
    o = (o + 255) & ~(size_t)255;
    void* p = ws + o;
    o += bytes;
    return p;
  };
  __half* feat1h = (__half*)alloc((size_t)NN * 64 * 2);
  float*  er1    = (float*)alloc((size_t)NN * 8 * 4);
  float*  h1     = (float*)alloc((size_t)NN * 64 * 4);
  int*    bcnt   = (int*)alloc((size_t)(NB) * 4);
  int*    bbase  = (int*)alloc((size_t)(NB+1) * 4);
  int*    cursor = (int*)alloc((size_t)NB * 4);
  int*    offs   = (int*)alloc((size_t)NN * 4);
  int*    deg    = (int*)alloc((size_t)NN * 4);
  int*    pairs  = (int*)alloc((size_t)NE * 4);
  int*    csr    = (int*)alloc((size_t)NE * 4);
  __half* w1frag = (__half*)alloc((size_t)16384 * 2);
  // aliases for buffers dead by the time they're reused
  __half* feat2p = (__half*)feat1h;       // padded [NN][64]: feat1 dead after agg1
  float*  er2    = er1;

  hipMemsetAsync(bcnt, 0, (size_t)NB * 4, stream);

  k_w1h  <<<64, 256, 0, stream>>>(W1, w1frag);
  k_gemm1<<<(NN + 63) / 64, 256, 0, stream>>>(x, w1frag, feat1h);
  k_er1  <<<3125, 256, 0, stream>>>(feat1h, ar1, er1);
  k_hist <<<NBLK, 256, 0, stream>>>(dst, bcnt);
  k_bscan<<<1, 256, 0, stream>>>(bcnt, bbase, cursor);
  k_binA <<<NBLK, 256, 0, stream>>>(src, dst, cursor, pairs);
  k_binB <<<NB, 256, 0, stream>>>(bbase, pairs, csr, offs, deg);
  k_agg1 <<<NN, 64, 0, stream>>>(feat1h, al1, er1, b1, offs, deg, csr, h1);
  k_gemm2<<<NN, 64, 0, stream>>>(h1, W2, al2, ar2, feat2p, er2);
  k_agg2 <<<NN, 64, 0, stream>>>(feat2p, er2, b2, offs, deg, csr, out);
}

// Round 21
// 282.095 us; speedup vs baseline: 1.1614x; 1.1614x over previous
//
#include <hip/hip_runtime.h>
#include <hip/hip_fp16.h>
#include <math.h>

#define NN 100000
#define NE 3200000
#define FIN 256
#define NEG 0.2f
#define BSH 7                 // 128 nodes per bucket
#define NB  782               // ceil(NN/128)
#define NBP 784               // padded
#define EPB 4096              // edges per binning block
#define NBLK 782              // ceil(NE/EPB)
#define CAPB 8192             // binB LDS capacity

typedef _Float16 h8 __attribute__((ext_vector_type(8)));
typedef float f32x4 __attribute__((ext_vector_type(4)));

// ---------------- W1 -> fp16 B-fragment layout ----------------
__global__ __launch_bounds__(256) void k_w1h(const float* __restrict__ W1,
                                             __half* __restrict__ w1frag) {
  int f = blockIdx.x * 256 + threadIdx.x;     // 64 blocks -> 16384
  int j = f & 7;
  int lane = (f >> 3) & 63;
  int g = f >> 9;                             // 0..31
  int ks = g & 7, ct = g >> 3;
  int k = ks * 32 + ((lane >> 4) & 3) * 8 + j;
  int c = ct * 16 + (lane & 15);
  w1frag[f] = __float2half(W1[k * 64 + c]);
}

// ---------------- GEMM1 via MFMA ----------------
__global__ __launch_bounds__(256) void k_gemm1(
    const float* __restrict__ x, const __half* __restrict__ w1frag,
    __half* __restrict__ feat1h) {
  const int lane = threadIdx.x & 63;
  const int wave = threadIdx.x >> 6;
  const int rowBase = blockIdx.x * 64 + wave * 16;
  const int arow = rowBase + (lane & 15);
  const int kc = lane >> 4;
  const bool act = (arow < NN);
  f32x4 acc0 = {0.f,0.f,0.f,0.f}, acc1 = {0.f,0.f,0.f,0.f};
  f32x4 acc2 = {0.f,0.f,0.f,0.f}, acc3 = {0.f,0.f,0.f,0.f};
  const float4* __restrict__ x4 = reinterpret_cast<const float4*>(x);
  const h8* __restrict__ wf = reinterpret_cast<const h8*>(w1frag);
#pragma unroll
  for (int ks = 0; ks < 8; ++ks) {
    h8 a;
    if (act) {
      float4 xa = x4[(size_t)arow * 64 + ks * 8 + kc * 2];
      float4 xb = x4[(size_t)arow * 64 + ks * 8 + kc * 2 + 1];
      a[0] = (_Float16)xa.x; a[1] = (_Float16)xa.y;
      a[2] = (_Float16)xa.z; a[3] = (_Float16)xa.w;
      a[4] = (_Float16)xb.x; a[5] = (_Float16)xb.y;
      a[6] = (_Float16)xb.z; a[7] = (_Float16)xb.w;
    } else {
#pragma unroll
      for (int j = 0; j < 8; ++j) a[j] = (_Float16)0.f;
    }
    h8 b0 = wf[(0 * 8 + ks) * 64 + lane];
    h8 b1 = wf[(1 * 8 + ks) * 64 + lane];
    h8 b2 = wf[(2 * 8 + ks) * 64 + lane];
    h8 b3 = wf[(3 * 8 + ks) * 64 + lane];
    acc0 = __builtin_amdgcn_mfma_f32_16x16x32_f16(a, b0, acc0, 0, 0, 0);
    acc1 = __builtin_amdgcn_mfma_f32_16x16x32_f16(a, b1, acc1, 0, 0, 0);
    acc2 = __builtin_amdgcn_mfma_f32_16x16x32_f16(a, b2, acc2, 0, 0, 0);
    acc3 = __builtin_amdgcn_mfma_f32_16x16x32_f16(a, b3, acc3, 0, 0, 0);
  }
  const int crow = rowBase + (lane >> 4) * 4;
  const int ccol = lane & 15;
#pragma unroll
  for (int r = 0; r < 4; ++r) {
    int row = crow + r;
    if (row < NN) {
      __half* fr = feat1h + (size_t)row * 64 + ccol;
      fr[0]  = __float2half(acc0[r]);
      fr[16] = __float2half(acc1[r]);
      fr[32] = __float2half(acc2[r]);
      fr[48] = __float2half(acc3[r]);
    }
  }
}

// ---------------- er1 from feat1h (el1 recomputed on the fly in agg1) ----------------
__global__ __launch_bounds__(256) void k_er1(
    const __half* __restrict__ feat1h, const float* __restrict__ ar1,
    float* __restrict__ er1) {
  const int g = blockIdx.x * 256 + threadIdx.x;   // 800000 = 3125*256
  const int n = g >> 3, h = g & 7;
  uint4 rv = *reinterpret_cast<const uint4*>(feat1h + (size_t)n * 64 + h * 8);
  float f[8];
  {
    unsigned w0 = rv.x, w1 = rv.y, w2 = rv.z, w3 = rv.w;
    float2 f0 = __half22float2(*reinterpret_cast<__half2*>(&w0));
    float2 f1 = __half22float2(*reinterpret_cast<__half2*>(&w1));
    float2 f2 = __half22float2(*reinterpret_cast<__half2*>(&w2));
    float2 f3 = __half22float2(*reinterpret_cast<__half2*>(&w3));
    f[0]=f0.x; f[1]=f0.y; f[2]=f1.x; f[3]=f1.y;
    f[4]=f2.x; f[5]=f2.y; f[6]=f3.x; f[7]=f3.y;
  }
  float pr = 0.f;
#pragma unroll
  for (int j = 0; j < 8; ++j) pr = fmaf(f[j], ar1[h * 8 + j], pr);
  er1[g] = pr;
}

// ---------------- bucket histogram ----------------
__global__ __launch_bounds__(256) void k_hist(const int* __restrict__ dst,
                                              int* __restrict__ bcnt) {
  __shared__ int lcnt[NBP];
  for (int i = threadIdx.x; i < NBP; i += 256) lcnt[i] = 0;
  __syncthreads();
  const int base = blockIdx.x * EPB;
  const int n = min(EPB, NE - base);
  for (int k = threadIdx.x; k < n; k += 256)
    atomicAdd(&lcnt[dst[base + k] >> BSH], 1);
  __syncthreads();
  for (int i = threadIdx.x; i < NB; i += 256)
    if (lcnt[i]) atomicAdd(&bcnt[i], lcnt[i]);
}

// ---------------- scan buckets -> bbase, cursor ----------------
__global__ __launch_bounds__(256) void k_bscan(const int* __restrict__ bcnt,
    int* __restrict__ bbase, int* __restrict__ cursor) {
  __shared__ int part[256];
  const int t = threadIdx.x;
  int v[4]; int s = 0;
#pragma unroll
  for (int j = 0; j < 4; ++j) { int i = t*4+j; v[j] = (i < NB) ? bcnt[i] : 0; s += v[j]; }
  part[t] = s; __syncthreads();
  for (int off = 1; off < 256; off <<= 1) {
    int a = (t >= off) ? part[t-off] : 0;
    __syncthreads(); part[t] += a; __syncthreads();
  }
  int excl = (t > 0) ? part[t-1] : 0;
#pragma unroll
  for (int j = 0; j < 4; ++j) {
    int i = t*4+j;
    if (i < NB) { bbase[i] = excl; cursor[i] = excl; }
    excl += v[j];
  }
  if (t == 255) bbase[NB] = part[255];   // == NE
}

// ---------------- phase A: bin edges by bucket (512 threads: 8 waves hide barrier latency) ----------------
__global__ __launch_bounds__(512) void k_binA(const int* __restrict__ src,
    const int* __restrict__ dst, int* __restrict__ cursor, int* __restrict__ pairs) {
  __shared__ int cnt[NBP];
  __shared__ int bstart[NBP + 1];   // exclusive starts; becomes bucket ENDs after scatter
  __shared__ int gbase[NBP];
  __shared__ int pack[EPB];
  __shared__ int wsum[8];
  const int t = threadIdx.x;
  const int base = blockIdx.x * EPB;
  const int n = min(EPB, NE - base);
  for (int i = t; i < NBP; i += 512) cnt[i] = 0;
  __syncthreads();
  for (int k = t; k < n; k += 512) atomicAdd(&cnt[dst[base+k] >> BSH], 1);
  __syncthreads();
  // exclusive scan cnt -> bstart: 2 buckets/thread, 8-wave shfl scan (2 barriers)
  int v0 = (t*2   < NBP) ? cnt[t*2]   : 0;
  int v1 = (t*2+1 < NBP) ? cnt[t*2+1] : 0;
  int s = v0 + v1;
  const int lanev = t & 63, wv = t >> 6;
  int inc = s;
#pragma unroll
  for (int dlt = 1; dlt < 64; dlt <<= 1) {
    int o = __shfl_up(inc, dlt);
    if (lanev >= dlt) inc += o;
  }
  if (lanev == 63) wsum[wv] = inc;
  __syncthreads();
  int wadd = 0;
  for (int w = 0; w < wv; ++w) wadd += wsum[w];
  int excl = wadd + inc - s;
  if (t*2   < NBP) bstart[t*2]   = excl;
  if (t*2+1 < NBP) bstart[t*2+1] = excl + v0;
  if (t == 511) bstart[NBP] = excl + s;   // == n (total)
  // reserve disjoint global ranges per bucket (cnt stable)
  for (int b = t; b < NB; b += 512)
    if (cnt[b]) gbase[b] = atomicAdd(&cursor[b], cnt[b]);
  __syncthreads();
  // local scatter: atomicAdd on bstart in place (bstart[b] -> end of bucket b)
  for (int k = t; k < n; k += 512) {
    int d = dst[base+k];
    int b = d >> BSH;
    int pos = atomicAdd(&bstart[b], 1);
    pack[pos] = src[base+k] | ((d & 127) << 20);
  }
  __syncthreads();
  // stream out: recover bucket via binary search over ends
  for (int i = t; i < n; i += 512) {
    int lo = 0, hi = NB - 1;
    while (lo < hi) {
      int mid = (lo + hi) >> 1;
      if (bstart[mid] > i) hi = mid; else lo = mid + 1;
    }
    const int b = lo;
    const int sb = (b > 0) ? bstart[b-1] : 0;   // post-scatter bstart[b-1] == original start of b
    pairs[gbase[b] + (i - sb)] = pack[i];
  }
}

// ---------------- phase B: per-bucket counting sort -> csr, offs, deg ----------------
__global__ __launch_bounds__(256) void k_binB(const int* __restrict__ bbase,
    const int* __restrict__ pairs, int* __restrict__ csr,
    int* __restrict__ offs, int* __restrict__ deg) {
  __shared__ int hist[128];
  __shared__ int incl[128];
  __shared__ int lcur[128];
  __shared__ int out[CAPB];
  const int b = blockIdx.x;
  const int t = threadIdx.x;
  const int lo = bbase[b], hi = bbase[b+1];
  const int n = hi - lo;
  if (t < 128) { hist[t] = 0; lcur[t] = 0; }
  __syncthreads();
  for (int k = t; k < n; k += 256) atomicAdd(&hist[(pairs[lo+k] >> 20) & 127], 1);
  __syncthreads();
  if (t < 128) incl[t] = hist[t];
  __syncthreads();
  for (int off = 1; off < 128; off <<= 1) {
    int a = (t < 128 && t >= off) ? incl[t-off] : 0;
    __syncthreads();
    if (t < 128) incl[t] += a;
    __syncthreads();
  }
  if (t < 128) {
    int gnode = b*128 + t;
    if (gnode < NN) {
      offs[gnode] = lo + ((t > 0) ? incl[t-1] : 0);
      deg[gnode]  = hist[t];
    }
  }
  __syncthreads();
  for (int k = t; k < n; k += 256) {
    int v = pairs[lo+k];
    int node = (v >> 20) & 127;
    int e = (node > 0) ? incl[node-1] : 0;
    int pos = e + atomicAdd(&lcur[node], 1);
    if (pos < CAPB) out[pos] = v & 0xFFFFF;
  }
  __syncthreads();
  for (int i = t; i < n && i < CAPB; i += 256) csr[lo+i] = out[i];
}

// ---------------- layer-1 aggregation: el computed on the fly from the gathered feat row ----------------
__global__ __launch_bounds__(64) void k_agg1(
    const __half* __restrict__ feat1h, const float* __restrict__ al1,
    const float* __restrict__ er1, const float* __restrict__ b1,
    const int* __restrict__ offs, const int* __restrict__ deg,
    const int* __restrict__ csr_src, float* __restrict__ h1) {
  const int d = blockIdx.x;
  const int lane = threadIdx.x;
  const int e8 = lane >> 3;    // edge slot 0..7
  const int h  = lane & 7;     // head 0..7
  const int off = offs[d];
  const int n = deg[d];
  const float erd = er1[d*8 + h];
  float a1[8];
#pragma unroll
  for (int k = 0; k < 8; ++k) a1[k] = al1[h*8 + k];
  int sAll = (lane < n) ? csr_src[off + lane] : 0;
  float ss = 0.f;
  float ac[8];
#pragma unroll
  for (int k = 0; k < 8; ++k) ac[k] = 0.f;
#pragma unroll 2
  for (int j0 = 0; j0 < n; j0 += 8) {
    const int j = j0 + e8;
    const bool act = (j < n);
    const int sreg = __shfl(sAll, j & 63);
    int s;
    if (j0 + 7 < 64) s = sreg;
    else s = act ? ((j < 64) ? sreg : csr_src[off + j]) : 0;
    uint4 rv = make_uint4(0u,0u,0u,0u);
    if (act) rv = *reinterpret_cast<const uint4*>(feat1h + (size_t)s*64 + h*8);
    float f[8];
    {
      unsigned w0 = rv.x, w1 = rv.y, w2 = rv.z, w3 = rv.w;
      float2 f0 = __half22float2(*reinterpret_cast<__half2*>(&w0));
      float2 f1 = __half22float2(*reinterpret_cast<__half2*>(&w1));
      float2 f2 = __half22float2(*reinterpret_cast<__half2*>(&w2));
      float2 f3 = __half22float2(*reinterpret_cast<__half2*>(&w3));
      f[0]=f0.x; f[1]=f0.y; f[2]=f1.x; f[3]=f1.y;
      f[4]=f2.x; f[5]=f2.y; f[6]=f3.x; f[7]=f3.y;
    }
    float elv = 0.f;
#pragma unroll
    for (int k = 0; k < 8; ++k) elv = fmaf(f[k], a1[k], elv);
    float t = elv + erd;
    float e = (t > 0.f) ? t : NEG * t;
    float p = act ? __expf(e) : 0.f;
    ss += p;
#pragma unroll
    for (int k = 0; k < 8; ++k) ac[k] = fmaf(p, f[k], ac[k]);
  }
#pragma unroll
  for (int msk = 8; msk < 64; msk <<= 1) {
    ss += __shfl_xor(ss, msk);
#pragma unroll
    for (int k = 0; k < 8; ++k) ac[k] += __shfl_xor(ac[k], msk);
  }
  if (e8 == 0) {
    float invS = (ss > 0.f) ? 1.f / ss : 0.f;
    float o[8];
#pragma unroll
    for (int k = 0; k < 8; ++k) {
      float v = ac[k] * invS + b1[h*8 + k];
      o[k] = (v > 0.f) ? v : 0.f;
    }
    float4* p4 = reinterpret_cast<float4*>(h1 + (size_t)d*64 + h*8);
    p4[0] = make_float4(o[0], o[1], o[2], o[3]);
    p4[1] = make_float4(o[4], o[5], o[6], o[7]);
  }
}

// ---------------- GEMM2: feat2p[N,64pad] = h1 @ W2; el2 (fp32) embedded at ch 40-41 ----------------
__global__ __launch_bounds__(64) void k_gemm2(
    const float* __restrict__ h1, const float* __restrict__ W2,
    const float* __restrict__ al2, const float* __restrict__ ar2,
    __half* __restrict__ feat2p, float* __restrict__ er2) {
  const int n = blockIdx.x;
  const int c = threadIdx.x;
  const float* __restrict__ hr = h1 + (size_t)n*64;
  float acc = 0.f;
  if (c < 40) {
    for (int k = 0; k < 64; ++k)
      acc = fmaf(hr[k], W2[k*40 + c], acc);
    feat2p[(size_t)n*64 + c] = __float2half(acc);   // 128-B aligned padded row
  } else if (c >= 42) {
    feat2p[(size_t)n*64 + c] = __ushort_as_half((unsigned short)0);
  }
  float pl = (c < 40) ? acc * al2[c] : 0.f;
  float pr = (c < 40) ? acc * ar2[c] : 0.f;
#pragma unroll
  for (int msk = 32; msk >= 1; msk >>= 1) {
    pl += __shfl_xor(pl, msk);
    pr += __shfl_xor(pr, msk);
  }
  if (c == 0) {
    er2[n] = pr;
    *reinterpret_cast<float*>(feat2p + (size_t)n*64 + 40) = pl;
  }
}

// ---------------- layer-2: single-pass no-max softmax, el2 read from padded row ----------------
__global__ __launch_bounds__(64) void k_agg2(
    const __half* __restrict__ feat2p,
    const float* __restrict__ er2, const float* __restrict__ b2,
    const int* __restrict__ offs, const int* __restrict__ deg,
    const int* __restrict__ csr_src, float* __restrict__ out) {
  const int d = blockIdx.x;
  const int lane = threadIdx.x;
  const int e8 = lane >> 3;    // edge slot 0..7
  const int q8 = lane & 7;     // 16-B chunk 0..7
  const bool ldr = (q8 < 6);   // chunks 0..5 loaded (5 = el2)
  const bool real = (q8 < 5);  // feat chunks
  const int off = offs[d];
  const int n = deg[d];
  const float erd = er2[d];
  const int elLane = e8 * 8 + 5;
  int sAll = (lane < n) ? csr_src[off + lane] : 0;
  float ss = 0.f;
  float ac[8];
#pragma unroll
  for (int k = 0; k < 8; ++k) ac[k] = 0.f;
#pragma unroll 2
  for (int j0 = 0; j0 < n; j0 += 8) {
    const int j = j0 + e8;
    const bool act = (j < n);
    const int sreg = __shfl(sAll, j & 63);
    int s;
    if (j0 + 7 < 64) s = sreg;
    else s = act ? ((j < 64) ? sreg : csr_src[off + j]) : 0;
    uint4 rv = make_uint4(0u,0u,0u,0u);
    if (act && ldr) rv = *reinterpret_cast<const uint4*>(feat2p + (size_t)s*64 + q8*8);
    float elv = __shfl(__int_as_float((int)rv.x), elLane);
    float f[8];
    {
      unsigned w0 = rv.x, w1 = rv.y, w2 = rv.z, w3 = rv.w;
      float2 f0 = __half22float2(*reinterpret_cast<__half2*>(&w0));
      float2 f1 = __half22float2(*reinterpret_cast<__half2*>(&w1));
      float2 f2 = __half22float2(*reinterpret_cast<__half2*>(&w2));
      float2 f3 = __half22float2(*reinterpret_cast<__half2*>(&w3));
      f[0]=f0.x; f[1]=f0.y; f[2]=f1.x; f[3]=f1.y;
      f[4]=f2.x; f[5]=f2.y; f[6]=f3.x; f[7]=f3.y;
    }
    float t = elv + erd;
    float e = (t > 0.f) ? t : NEG * t;
    float p = act ? __expf(e) : 0.f;
    ss += p;
#pragma unroll
    for (int k = 0; k < 8; ++k) ac[k] = fmaf(p, f[k], ac[k]);
  }
#pragma unroll
  for (int msk = 8; msk < 64; msk <<= 1) {
    ss += __shfl_xor(ss, msk);
#pragma unroll
    for (int k = 0; k < 8; ++k) ac[k] += __shfl_xor(ac[k], msk);
  }
  if (e8 == 0 && real) {
    float invS = (ss > 0.f) ? 1.f / ss : 0.f;
    float o[8];
#pragma unroll
    for (int k = 0; k < 8; ++k) o[k] = ac[k] * invS + b2[q8*8 + k];
    float* po = out + (size_t)d*40 + q8*8;
#pragma unroll
    for (int k = 0; k < 8; ++k) po[k] = o[k];
  }
}

extern "C" void kernel_launch(void* const* d_in, const int* in_sizes, int n_in,
                              void* d_out, int out_size, void* d_ws, size_t ws_size,
                              hipStream_t stream) {
  const float* x   = (const float*)d_in[0];
  const float* W1  = (const float*)d_in[1];
  const float* al1 = (const float*)d_in[2];
  const float* ar1 = (const float*)d_in[3];
  const float* b1  = (const float*)d_in[4];
  const float* W2  = (const float*)d_in[5];
  const float* al2 = (const float*)d_in[6];
  const float* ar2 = (const float*)d_in[7];
  const float* b2  = (const float*)d_in[8];
  const int* src   = (const int*)d_in[9];
  const int* dst   = (const int*)d_in[10];
  float* out = (float*)d_out;

  char* ws = (char*)d_ws;
  size_t o = 0;
  auto alloc = [&](size_t bytes) -> void* {
    o = (o + 255) & ~(size_t)255;
    void* p = ws + o;
    o += bytes;
    return p;
  };
  __half* feat1h = (__half*)alloc((size_t)NN * 64 * 2);
  float*  er1    = (float*)alloc((size_t)NN * 8 * 4);
  float*  h1     = (float*)alloc((size_t)NN * 64 * 4);
  int*    bcnt   = (int*)alloc((size_t)(NB) * 4);
  int*    bbase  = (int*)alloc((size_t)(NB+1) * 4);
  int*    cursor = (int*)alloc((size_t)NB * 4);
  int*    offs   = (int*)alloc((size_t)NN * 4);
  int*    deg    = (int*)alloc((size_t)NN * 4);
  int*    pairs  = (int*)alloc((size_t)NE * 4);
  int*    csr    = (int*)alloc((size_t)NE * 4);
  __half* w1frag = (__half*)alloc((size_t)16384 * 2);
  // aliases for buffers dead by the time they're reused
  __half* feat2p = (__half*)feat1h;       // padded [NN][64]: feat1 dead after agg1
  float*  er2    = er1;

  hipMemsetAsync(bcnt, 0, (size_t)NB * 4, stream);

  k_w1h  <<<64, 256, 0, stream>>>(W1, w1frag);
  k_gemm1<<<(NN + 63) / 64, 256, 0, stream>>>(x, w1frag, feat1h);
  k_er1  <<<3125, 256, 0, stream>>>(feat1h, ar1, er1);
  k_hist <<<NBLK, 256, 0, stream>>>(dst, bcnt);
  k_bscan<<<1, 256, 0, stream>>>(bcnt, bbase, cursor);
  k_binA <<<NBLK, 512, 0, stream>>>(src, dst, cursor, pairs);
  k_binB <<<NB, 256, 0, stream>>>(bbase, pairs, csr, offs, deg);
  k_agg1 <<<NN, 64, 0, stream>>>(feat1h, al1, er1, b1, offs, deg, csr, h1);
  k_gemm2<<<NN, 64, 0, stream>>>(h1, W2, al2, ar2, feat2p, er2);
  k_agg2 <<<NN, 64, 0, stream>>>(feat2p, er2, b2, offs, deg, csr, out);
}

// Round 22
// 276.540 us; speedup vs baseline: 1.1848x; 1.0201x over previous
//
#include <hip/hip_runtime.h>
#include <hip/hip_fp16.h>
#include <math.h>

#define NN 100000
#define NE 3200000
#define FIN 256
#define NEG 0.2f
#define BSH 7                 // 128 nodes per bucket
#define NB  782               // ceil(NN/128)
#define NBP 784               // padded
#define EPB 4096              // edges per binning block
#define NBLK 782              // ceil(NE/EPB)
#define CAPB 8192             // binB LDS capacity

typedef _Float16 h8 __attribute__((ext_vector_type(8)));
typedef _Float16 h2 __attribute__((ext_vector_type(2)));
typedef float f32x4 __attribute__((ext_vector_type(4)));

// ---------------- W1 -> fp16 B-fragment layout ----------------
__global__ __launch_bounds__(256) void k_w1h(const float* __restrict__ W1,
                                             __half* __restrict__ w1frag) {
  int f = blockIdx.x * 256 + threadIdx.x;     // 64 blocks -> 16384
  int j = f & 7;
  int lane = (f >> 3) & 63;
  int g = f >> 9;                             // 0..31
  int ks = g & 7, ct = g >> 3;
  int k = ks * 32 + ((lane >> 4) & 3) * 8 + j;
  int c = ct * 16 + (lane & 15);
  w1frag[f] = __float2half(W1[k * 64 + c]);
}

// ---------------- GEMM1 via MFMA + fused dst histogram ----------------
__global__ __launch_bounds__(256) void k_gemm1(
    const float* __restrict__ x, const __half* __restrict__ w1frag,
    const int* __restrict__ dst, int* __restrict__ bcnt,
    __half* __restrict__ feat1h) {
  __shared__ int lcnt[NBP];
  const int lane = threadIdx.x & 63;
  const int wave = threadIdx.x >> 6;
  const int rowBase = blockIdx.x * 64 + wave * 16;
  const int arow = rowBase + (lane & 15);
  const int kc = lane >> 4;
  const bool act = (arow < NN);
  f32x4 acc0 = {0.f,0.f,0.f,0.f}, acc1 = {0.f,0.f,0.f,0.f};
  f32x4 acc2 = {0.f,0.f,0.f,0.f}, acc3 = {0.f,0.f,0.f,0.f};
  const float4* __restrict__ x4 = reinterpret_cast<const float4*>(x);
  const h8* __restrict__ wf = reinterpret_cast<const h8*>(w1frag);
#pragma unroll
  for (int ks = 0; ks < 8; ++ks) {
    h8 a;
    if (act) {
      float4 xa = x4[(size_t)arow * 64 + ks * 8 + kc * 2];
      float4 xb = x4[(size_t)arow * 64 + ks * 8 + kc * 2 + 1];
      a[0] = (_Float16)xa.x; a[1] = (_Float16)xa.y;
      a[2] = (_Float16)xa.z; a[3] = (_Float16)xa.w;
      a[4] = (_Float16)xb.x; a[5] = (_Float16)xb.y;
      a[6] = (_Float16)xb.z; a[7] = (_Float16)xb.w;
    } else {
#pragma unroll
      for (int j = 0; j < 8; ++j) a[j] = (_Float16)0.f;
    }
    h8 b0 = wf[(0 * 8 + ks) * 64 + lane];
    h8 b1 = wf[(1 * 8 + ks) * 64 + lane];
    h8 b2 = wf[(2 * 8 + ks) * 64 + lane];
    h8 b3 = wf[(3 * 8 + ks) * 64 + lane];
    acc0 = __builtin_amdgcn_mfma_f32_16x16x32_f16(a, b0, acc0, 0, 0, 0);
    acc1 = __builtin_amdgcn_mfma_f32_16x16x32_f16(a, b1, acc1, 0, 0, 0);
    acc2 = __builtin_amdgcn_mfma_f32_16x16x32_f16(a, b2, acc2, 0, 0, 0);
    acc3 = __builtin_amdgcn_mfma_f32_16x16x32_f16(a, b3, acc3, 0, 0, 0);
  }
  const int crow = rowBase + (lane >> 4) * 4;
  const int ccol = lane & 15;
#pragma unroll
  for (int r = 0; r < 4; ++r) {
    int row = crow + r;
    if (row < NN) {
      __half* fr = feat1h + (size_t)row * 64 + ccol;
      fr[0]  = __float2half(acc0[r]);
      fr[16] = __float2half(acc1[r]);
      fr[32] = __float2half(acc2[r]);
      fr[48] = __float2half(acc3[r]);
    }
  }
  // fused dst histogram: first NBLK blocks each cover EPB edges
  if (blockIdx.x < NBLK) {
    const int t = threadIdx.x;
    for (int i = t; i < NBP; i += 256) lcnt[i] = 0;
    __syncthreads();
    const int hbase = blockIdx.x * EPB;
    const int hn = min(EPB, NE - hbase);
    for (int k = t; k < hn; k += 256)
      atomicAdd(&lcnt[dst[hbase + k] >> BSH], 1);
    __syncthreads();
    for (int i = t; i < NB; i += 256)
      if (lcnt[i]) atomicAdd(&bcnt[i], lcnt[i]);
  }
}

// ---------------- er1 from feat1h (el1 recomputed on the fly in agg1) ----------------
__global__ __launch_bounds__(256) void k_er1(
    const __half* __restrict__ feat1h, const float* __restrict__ ar1,
    float* __restrict__ er1) {
  const int g = blockIdx.x * 256 + threadIdx.x;   // 800000 = 3125*256
  const int n = g >> 3, h = g & 7;
  uint4 rv = *reinterpret_cast<const uint4*>(feat1h + (size_t)n * 64 + h * 8);
  float f[8];
  {
    unsigned w0 = rv.x, w1 = rv.y, w2 = rv.z, w3 = rv.w;
    float2 f0 = __half22float2(*reinterpret_cast<__half2*>(&w0));
    float2 f1 = __half22float2(*reinterpret_cast<__half2*>(&w1));
    float2 f2 = __half22float2(*reinterpret_cast<__half2*>(&w2));
    float2 f3 = __half22float2(*reinterpret_cast<__half2*>(&w3));
    f[0]=f0.x; f[1]=f0.y; f[2]=f1.x; f[3]=f1.y;
    f[4]=f2.x; f[5]=f2.y; f[6]=f3.x; f[7]=f3.y;
  }
  float pr = 0.f;
#pragma unroll
  for (int j = 0; j < 8; ++j) pr = fmaf(f[j], ar1[h * 8 + j], pr);
  er1[g] = pr;
}

// ---------------- scan buckets -> bbase, cursor ----------------
__global__ __launch_bounds__(256) void k_bscan(const int* __restrict__ bcnt,
    int* __restrict__ bbase, int* __restrict__ cursor) {
  __shared__ int part[256];
  const int t = threadIdx.x;
  int v[4]; int s = 0;
#pragma unroll
  for (int j = 0; j < 4; ++j) { int i = t*4+j; v[j] = (i < NB) ? bcnt[i] : 0; s += v[j]; }
  part[t] = s; __syncthreads();
  for (int off = 1; off < 256; off <<= 1) {
    int a = (t >= off) ? part[t-off] : 0;
    __syncthreads(); part[t] += a; __syncthreads();
  }
  int excl = (t > 0) ? part[t-1] : 0;
#pragma unroll
  for (int j = 0; j < 4; ++j) {
    int i = t*4+j;
    if (i < NB) { bbase[i] = excl; cursor[i] = excl; }
    excl += v[j];
  }
  if (t == 255) bbase[NB] = part[255];   // == NE
}

// ---------------- phase A: bin edges by bucket (512 threads: 8 waves hide barrier latency) ----------------
__global__ __launch_bounds__(512) void k_binA(const int* __restrict__ src,
    const int* __restrict__ dst, int* __restrict__ cursor, int* __restrict__ pairs) {
  __shared__ int cnt[NBP];
  __shared__ int bstart[NBP + 1];   // exclusive starts; becomes bucket ENDs after scatter
  __shared__ int gbase[NBP];
  __shared__ int pack[EPB];
  __shared__ int wsum[8];
  const int t = threadIdx.x;
  const int base = blockIdx.x * EPB;
  const int n = min(EPB, NE - base);
  for (int i = t; i < NBP; i += 512) cnt[i] = 0;
  __syncthreads();
  for (int k = t; k < n; k += 512) atomicAdd(&cnt[dst[base+k] >> BSH], 1);
  __syncthreads();
  // exclusive scan cnt -> bstart: 2 buckets/thread, 8-wave shfl scan (2 barriers)
  int v0 = (t*2   < NBP) ? cnt[t*2]   : 0;
  int v1 = (t*2+1 < NBP) ? cnt[t*2+1] : 0;
  int s = v0 + v1;
  const int lanev = t & 63, wv = t >> 6;
  int inc = s;
#pragma unroll
  for (int dlt = 1; dlt < 64; dlt <<= 1) {
    int o = __shfl_up(inc, dlt);
    if (lanev >= dlt) inc += o;
  }
  if (lanev == 63) wsum[wv] = inc;
  __syncthreads();
  int wadd = 0;
  for (int w = 0; w < wv; ++w) wadd += wsum[w];
  int excl = wadd + inc - s;
  if (t*2   < NBP) bstart[t*2]   = excl;
  if (t*2+1 < NBP) bstart[t*2+1] = excl + v0;
  if (t == 511) bstart[NBP] = excl + s;   // == n (total)
  // reserve disjoint global ranges per bucket (cnt stable)
  for (int b = t; b < NB; b += 512)
    if (cnt[b]) gbase[b] = atomicAdd(&cursor[b], cnt[b]);
  __syncthreads();
  // local scatter: atomicAdd on bstart in place (bstart[b] -> end of bucket b)
  for (int k = t; k < n; k += 512) {
    int d = dst[base+k];
    int b = d >> BSH;
    int pos = atomicAdd(&bstart[b], 1);
    pack[pos] = src[base+k] | ((d & 127) << 20);
  }
  __syncthreads();
  // stream out: recover bucket via binary search over ends
  for (int i = t; i < n; i += 512) {
    int lo = 0, hi = NB - 1;
    while (lo < hi) {
      int mid = (lo + hi) >> 1;
      if (bstart[mid] > i) hi = mid; else lo = mid + 1;
    }
    const int b = lo;
    const int sb = (b > 0) ? bstart[b-1] : 0;   // post-scatter bstart[b-1] == original start of b
    pairs[gbase[b] + (i - sb)] = pack[i];
  }
}

// ---------------- phase B: per-bucket counting sort -> csr, offs, deg ----------------
__global__ __launch_bounds__(256) void k_binB(const int* __restrict__ bbase,
    const int* __restrict__ pairs, int* __restrict__ csr,
    int* __restrict__ offs, int* __restrict__ deg) {
  __shared__ int hist[128];
  __shared__ int incl[128];
  __shared__ int lcur[128];
  __shared__ int out[CAPB];
  const int b = blockIdx.x;
  const int t = threadIdx.x;
  const int lo = bbase[b], hi = bbase[b+1];
  const int n = hi - lo;
  if (t < 128) { hist[t] = 0; lcur[t] = 0; }
  __syncthreads();
  for (int k = t; k < n; k += 256) atomicAdd(&hist[(pairs[lo+k] >> 20) & 127], 1);
  __syncthreads();
  if (t < 128) incl[t] = hist[t];
  __syncthreads();
  for (int off = 1; off < 128; off <<= 1) {
    int a = (t < 128 && t >= off) ? incl[t-off] : 0;
    __syncthreads();
    if (t < 128) incl[t] += a;
    __syncthreads();
  }
  if (t < 128) {
    int gnode = b*128 + t;
    if (gnode < NN) {
      offs[gnode] = lo + ((t > 0) ? incl[t-1] : 0);
      deg[gnode]  = hist[t];
    }
  }
  __syncthreads();
  for (int k = t; k < n; k += 256) {
    int v = pairs[lo+k];
    int node = (v >> 20) & 127;
    int e = (node > 0) ? incl[node-1] : 0;
    int pos = e + atomicAdd(&lcur[node], 1);
    if (pos < CAPB) out[pos] = v & 0xFFFFF;
  }
  __syncthreads();
  for (int i = t; i < n && i < CAPB; i += 256) csr[lo+i] = out[i];
}

// ---------------- layer-1 aggregation: el via fdot2 on raw halves ----------------
__global__ __launch_bounds__(64) void k_agg1(
    const __half* __restrict__ feat1h, const float* __restrict__ al1,
    const float* __restrict__ er1, const float* __restrict__ b1,
    const int* __restrict__ offs, const int* __restrict__ deg,
    const int* __restrict__ csr_src, float* __restrict__ h1) {
  const int d = blockIdx.x;
  const int lane = threadIdx.x;
  const int e8 = lane >> 3;    // edge slot 0..7
  const int h  = lane & 7;     // head 0..7
  const int off = offs[d];
  const int n = deg[d];
  const float erd = er1[d*8 + h];
#if __has_builtin(__builtin_amdgcn_fdot2)
  h2 a1h[4];
#pragma unroll
  for (int k = 0; k < 4; ++k) {
    a1h[k][0] = (_Float16)al1[h*8 + 2*k];
    a1h[k][1] = (_Float16)al1[h*8 + 2*k + 1];
  }
#else
  float a1[8];
#pragma unroll
  for (int k = 0; k < 8; ++k) a1[k] = al1[h*8 + k];
#endif
  int sAll = (lane < n) ? csr_src[off + lane] : 0;
  float ss = 0.f;
  float ac[8];
#pragma unroll
  for (int k = 0; k < 8; ++k) ac[k] = 0.f;
#pragma unroll 2
  for (int j0 = 0; j0 < n; j0 += 8) {
    const int j = j0 + e8;
    const bool act = (j < n);
    const int sreg = __shfl(sAll, j & 63);
    int s;
    if (j0 + 7 < 64) s = sreg;
    else s = act ? ((j < 64) ? sreg : csr_src[off + j]) : 0;
    uint4 rv = make_uint4(0u,0u,0u,0u);
    if (act) rv = *reinterpret_cast<const uint4*>(feat1h + (size_t)s*64 + h*8);
    float f[8];
    {
      unsigned w0 = rv.x, w1 = rv.y, w2 = rv.z, w3 = rv.w;
      float2 f0 = __half22float2(*reinterpret_cast<__half2*>(&w0));
      float2 f1 = __half22float2(*reinterpret_cast<__half2*>(&w1));
      float2 f2 = __half22float2(*reinterpret_cast<__half2*>(&w2));
      float2 f3 = __half22float2(*reinterpret_cast<__half2*>(&w3));
      f[0]=f0.x; f[1]=f0.y; f[2]=f1.x; f[3]=f1.y;
      f[4]=f2.x; f[5]=f2.y; f[6]=f3.x; f[7]=f3.y;
    }
    float elv = 0.f;
#if __has_builtin(__builtin_amdgcn_fdot2)
    {
      h2 hv0 = *reinterpret_cast<h2*>(&rv.x);
      h2 hv1 = *reinterpret_cast<h2*>(&rv.y);
      h2 hv2 = *reinterpret_cast<h2*>(&rv.z);
      h2 hv3 = *reinterpret_cast<h2*>(&rv.w);
      elv = __builtin_amdgcn_fdot2(hv0, a1h[0], elv, false);
      elv = __builtin_amdgcn_fdot2(hv1, a1h[1], elv, false);
      elv = __builtin_amdgcn_fdot2(hv2, a1h[2], elv, false);
      elv = __builtin_amdgcn_fdot2(hv3, a1h[3], elv, false);
    }
#else
#pragma unroll
    for (int k = 0; k < 8; ++k) elv = fmaf(f[k], a1[k], elv);
#endif
    float t = elv + erd;
    float e = (t > 0.f) ? t : NEG * t;
    float p = act ? __expf(e) : 0.f;
    ss += p;
#pragma unroll
    for (int k = 0; k < 8; ++k) ac[k] = fmaf(p, f[k], ac[k]);
  }
#pragma unroll
  for (int msk = 8; msk < 64; msk <<= 1) {
    ss += __shfl_xor(ss, msk);
#pragma unroll
    for (int k = 0; k < 8; ++k) ac[k] += __shfl_xor(ac[k], msk);
  }
  if (e8 == 0) {
    float invS = (ss > 0.f) ? 1.f / ss : 0.f;
    float o[8];
#pragma unroll
    for (int k = 0; k < 8; ++k) {
      float v = ac[k] * invS + b1[h*8 + k];
      o[k] = (v > 0.f) ? v : 0.f;
    }
    float4* p4 = reinterpret_cast<float4*>(h1 + (size_t)d*64 + h*8);
    p4[0] = make_float4(o[0], o[1], o[2], o[3]);
    p4[1] = make_float4(o[4], o[5], o[6], o[7]);
  }
}

// ---------------- GEMM2: feat2p[N,64pad] = h1 @ W2; el2 (fp32) embedded at ch 40-41 ----------------
__global__ __launch_bounds__(64) void k_gemm2(
    const float* __restrict__ h1, const float* __restrict__ W2,
    const float* __restrict__ al2, const float* __restrict__ ar2,
    __half* __restrict__ feat2p, float* __restrict__ er2) {
  const int n = blockIdx.x;
  const int c = threadIdx.x;
  const float* __restrict__ hr = h1 + (size_t)n*64;
  float acc = 0.f;
  if (c < 40) {
    for (int k = 0; k < 64; ++k)
      acc = fmaf(hr[k], W2[k*40 + c], acc);
    feat2p[(size_t)n*64 + c] = __float2half(acc);   // 128-B aligned padded row
  } else if (c >= 42) {
    feat2p[(size_t)n*64 + c] = __ushort_as_half((unsigned short)0);
  }
  float pl = (c < 40) ? acc * al2[c] : 0.f;
  float pr = (c < 40) ? acc * ar2[c] : 0.f;
#pragma unroll
  for (int msk = 32; msk >= 1; msk >>= 1) {
    pl += __shfl_xor(pl, msk);
    pr += __shfl_xor(pr, msk);
  }
  if (c == 0) {
    er2[n] = pr;
    *reinterpret_cast<float*>(feat2p + (size_t)n*64 + 40) = pl;
  }
}

// ---------------- layer-2: single-pass no-max softmax, el2 read from padded row ----------------
__global__ __launch_bounds__(64) void k_agg2(
    const __half* __restrict__ feat2p,
    const float* __restrict__ er2, const float* __restrict__ b2,
    const int* __restrict__ offs, const int* __restrict__ deg,
    const int* __restrict__ csr_src, float* __restrict__ out) {
  const int d = blockIdx.x;
  const int lane = threadIdx.x;
  const int e8 = lane >> 3;    // edge slot 0..7
  const int q8 = lane & 7;     // 16-B chunk 0..7
  const bool ldr = (q8 < 6);   // chunks 0..5 loaded (5 = el2)
  const bool real = (q8 < 5);  // feat chunks
  const int off = offs[d];
  const int n = deg[d];
  const float erd = er2[d];
  const int elLane = e8 * 8 + 5;
  int sAll = (lane < n) ? csr_src[off + lane] : 0;
  float ss = 0.f;
  float ac[8];
#pragma unroll
  for (int k = 0; k < 8; ++k) ac[k] = 0.f;
#pragma unroll 2
  for (int j0 = 0; j0 < n; j0 += 8) {
    const int j = j0 + e8;
    const bool act = (j < n);
    const int sreg = __shfl(sAll, j & 63);
    int s;
    if (j0 + 7 < 64) s = sreg;
    else s = act ? ((j < 64) ? sreg : csr_src[off + j]) : 0;
    uint4 rv = make_uint4(0u,0u,0u,0u);
    if (act && ldr) rv = *reinterpret_cast<const uint4*>(feat2p + (size_t)s*64 + q8*8);
    float elv = __shfl(__int_as_float((int)rv.x), elLane);
    float f[8];
    {
      unsigned w0 = rv.x, w1 = rv.y, w2 = rv.z, w3 = rv.w;
      float2 f0 = __half22float2(*reinterpret_cast<__half2*>(&w0));
      float2 f1 = __half22float2(*reinterpret_cast<__half2*>(&w1));
      float2 f2 = __half22float2(*reinterpret_cast<__half2*>(&w2));
      float2 f3 = __half22float2(*reinterpret_cast<__half2*>(&w3));
      f[0]=f0.x; f[1]=f0.y; f[2]=f1.x; f[3]=f1.y;
      f[4]=f2.x; f[5]=f2.y; f[6]=f3.x; f[7]=f3.y;
    }
    float t = elv + erd;
    float e = (t > 0.f) ? t : NEG * t;
    float p = act ? __expf(e) : 0.f;
    ss += p;
#pragma unroll
    for (int k = 0; k < 8; ++k) ac[k] = fmaf(p, f[k], ac[k]);
  }
#pragma unroll
  for (int msk = 8; msk < 64; msk <<= 1) {
    ss += __shfl_xor(ss, msk);
#pragma unroll
    for (int k = 0; k < 8; ++k) ac[k] += __shfl_xor(ac[k], msk);
  }
  if (e8 == 0 && real) {
    float invS = (ss > 0.f) ? 1.f / ss : 0.f;
    float o[8];
#pragma unroll
    for (int k = 0; k < 8; ++k) o[k] = ac[k] * invS + b2[q8*8 + k];
    float* po = out + (size_t)d*40 + q8*8;
#pragma unroll
    for (int k = 0; k < 8; ++k) po[k] = o[k];
  }
}

extern "C" void kernel_launch(void* const* d_in, const int* in_sizes, int n_in,
                              void* d_out, int out_size, void* d_ws, size_t ws_size,
                              hipStream_t stream) {
  const float* x   = (const float*)d_in[0];
  const float* W1  = (const float*)d_in[1];
  const float* al1 = (const float*)d_in[2];
  const float* ar1 = (const float*)d_in[3];
  const float* b1  = (const float*)d_in[4];
  const float* W2  = (const float*)d_in[5];
  const float* al2 = (const float*)d_in[6];
  const float* ar2 = (const float*)d_in[7];
  const float* b2  = (const float*)d_in[8];
  const int* src   = (const int*)d_in[9];
  const int* dst   = (const int*)d_in[10];
  float* out = (float*)d_out;

  char* ws = (char*)d_ws;
  size_t o = 0;
  auto alloc = [&](size_t bytes) -> void* {
    o = (o + 255) & ~(size_t)255;
    void* p = ws + o;
    o += bytes;
    return p;
  };
  __half* feat1h = (__half*)alloc((size_t)NN * 64 * 2);
  float*  er1    = (float*)alloc((size_t)NN * 8 * 4);
  float*  h1     = (float*)alloc((size_t)NN * 64 * 4);
  int*    bcnt   = (int*)alloc((size_t)(NB) * 4);
  int*    bbase  = (int*)alloc((size_t)(NB+1) * 4);
  int*    cursor = (int*)alloc((size_t)NB * 4);
  int*    offs   = (int*)alloc((size_t)NN * 4);
  int*    deg    = (int*)alloc((size_t)NN * 4);
  int*    pairs  = (int*)alloc((size_t)NE * 4);
  int*    csr    = (int*)alloc((size_t)NE * 4);
  __half* w1frag = (__half*)alloc((size_t)16384 * 2);
  // aliases for buffers dead by the time they're reused
  __half* feat2p = (__half*)feat1h;       // padded [NN][64]: feat1 dead after agg1
  float*  er2    = er1;

  hipMemsetAsync(bcnt, 0, (size_t)NB * 4, stream);

  k_w1h  <<<64, 256, 0, stream>>>(W1, w1frag);
  k_gemm1<<<(NN + 63) / 64, 256, 0, stream>>>(x, w1frag, dst, bcnt, feat1h);
  k_er1  <<<3125, 256, 0, stream>>>(feat1h, ar1, er1);
  k_bscan<<<1, 256, 0, stream>>>(bcnt, bbase, cursor);
  k_binA <<<NBLK, 512, 0, stream>>>(src, dst, cursor, pairs);
  k_binB <<<NB, 256, 0, stream>>>(bbase, pairs, csr, offs, deg);
  k_agg1 <<<NN, 64, 0, stream>>>(feat1h, al1, er1, b1, offs, deg, csr, h1);
  k_gemm2<<<NN, 64, 0, stream>>>(h1, W2, al2, ar2, feat2p, er2);
  k_agg2 <<<NN, 64, 0, stream>>>(feat2p, er2, b2, offs, deg, csr, out);
}